// Round 10
// baseline (729.912 us; speedup 1.0000x reference)
//
#include <hip/hip_runtime.h>
#include <hip/hip_bf16.h>

#define N_NODES 100000
#define N_EDGES 1600000
#define HDIM    128
#define NGRAPH  1000
#define NCLASS  10
#define BN_EPS  1e-5f

#define BSHIFT  7
#define BMASK   127
#define NBUCKET 782          // ceil(N_NODES / 128)
#define TILE3   8192         // edges per scatter block
#define NSB     196          // ceil(N_EDGES / TILE3)
#define GATHER_BLOCKS 1024   // measured: 2048 regresses (L2 contention)

typedef short short8_t __attribute__((ext_vector_type(8)));
typedef float f32x4_t  __attribute__((ext_vector_type(4)));

// ---------- bf16 helpers (manual, RNE) ----------
__device__ __forceinline__ float bf2f(ushort u) {
    union { unsigned int i; float f; } v; v.i = ((unsigned int)u) << 16; return v.f;
}
__device__ __forceinline__ ushort f2bf(float f) {
    union { float f; unsigned int i; } v; v.f = f;
    unsigned int i = v.i;
    unsigned int r = i + 0x7fffu + ((i >> 16) & 1u);
    return (ushort)(r >> 16);
}
__device__ __forceinline__ unsigned int pack2(float a, float b) {
    return (unsigned int)f2bf(a) | ((unsigned int)f2bf(b) << 16);
}
__device__ __forceinline__ float lo16(unsigned int u) {
    union { unsigned int i; float f; } v; v.i = u << 16; return v.f;
}
__device__ __forceinline__ float hi16(unsigned int u) {
    union { unsigned int i; float f; } v; v.i = u & 0xffff0000u; return v.f;
}

// ---------- 1a. fused: W^T bf16 prep (blocks 0..47) + per-block bucket histogram ----------
__global__ __launch_bounds__(256)
void wprep_hist(const float* __restrict__ W, ushort* __restrict__ wtbT,
                const int* __restrict__ dst, int* __restrict__ blockhist) {
    __shared__ int h[NBUCKET];
    int t = threadIdx.x;
    if (blockIdx.x < 48) {
        int l = blockIdx.x >> 4, slice = blockIdx.x & 15;
        int idx = slice * 1024 + t * 4;
        int k = idx >> 7, n = idx & 127;
        float4 w4 = *(const float4*)&W[(size_t)l * 16384 + k * 128 + n];
        ushort* o = wtbT + (size_t)l * 16384;
        o[(n + 0) * 128 + k] = f2bf(w4.x);
        o[(n + 1) * 128 + k] = f2bf(w4.y);
        o[(n + 2) * 128 + k] = f2bf(w4.z);
        o[(n + 3) * 128 + k] = f2bf(w4.w);
        return;
    }
    int blk = blockIdx.x - 48;
    for (int i = t; i < NBUCKET; i += 256) h[i] = 0;
    __syncthreads();
    long tile0 = (long)blk * TILE3;
    #pragma unroll 4
    for (int i = 0; i < TILE3 / 256; i++) {
        long e = tile0 + t + i * 256;
        if (e < N_EDGES) atomicAdd(&h[dst[e] >> BSHIFT], 1);
    }
    __syncthreads();
    for (int b = t; b < NBUCKET; b += 256)
        blockhist[(size_t)b * NSB + blk] = h[b];
}

// ---------- 1b. per-bucket scan across scatter blocks: one wave per bucket ----------
__global__ __launch_bounds__(64)
void col_scan(int* __restrict__ blockhist, int* __restrict__ coltotal) {
    int b = blockIdx.x;
    int lane = threadIdx.x;
    int base = b * NSB;
    int carry = 0;
    for (int r = 0; r < NSB; r += 64) {
        int i = r + lane;
        int v = (i < NSB) ? blockhist[base + i] : 0;
        int x = v;
        #pragma unroll
        for (int off = 1; off < 64; off <<= 1) {
            int y = __shfl_up(x, off, 64);
            if (lane >= off) x += y;
        }
        if (i < NSB) blockhist[base + i] = carry + x - v;
        carry += __shfl(x, 63, 64);
    }
    if (lane == 0) coltotal[b] = carry;
}

// ---------- 1c. bucket scan (one block) + zero-init BN slots/counters ----------
__global__ __launch_bounds__(1024)
void bucket_scan(const int* __restrict__ coltotal, int* __restrict__ bucket_base,
                 int* __restrict__ row_start, float* __restrict__ slotbuf,
                 int* __restrict__ counters) {
    __shared__ int wsum[16];
    int t = threadIdx.x, lane = t & 63, wid = t >> 6;
    int v = (t < NBUCKET) ? coltotal[t] : 0;
    int x = v;
    #pragma unroll
    for (int off = 1; off < 64; off <<= 1) {
        int y = __shfl_up(x, off, 64);
        if (lane >= off) x += y;
    }
    if (lane == 63) wsum[wid] = x;
    __syncthreads();
    if (t == 0) {
        int s = 0;
        #pragma unroll
        for (int w = 0; w < 16; w++) { int tmp = wsum[w]; wsum[w] = s; s += tmp; }
    }
    __syncthreads();
    int excl = wsum[wid] + (x - v);
    if (t < NBUCKET) bucket_base[t] = excl;
    if (t == 0) { bucket_base[NBUCKET] = N_EDGES; row_start[N_NODES] = N_EDGES; }
    // zero BN stat slots (3 layers x 2 x 16 slots x 128 feats) and tail counters
    for (int i = t; i < 3 * 2 * 16 * 128; i += 1024) slotbuf[i] = 0.f;
    if (t < 3) counters[t] = 0;
}

// ---------- 1d. scatter: single pass, no re-hist, no global atomics ----------
__global__ __launch_bounds__(256)
void scatter_pairs(const int* __restrict__ src, const int* __restrict__ dst,
                   const int* __restrict__ bucket_base, const int* __restrict__ blockhist,
                   unsigned int* __restrict__ pairs) {
    __shared__ int lbase[NBUCKET];
    __shared__ int lcur[NBUCKET];
    int t = threadIdx.x;
    int blk = blockIdx.x;
    for (int b = t; b < NBUCKET; b += 256) {
        lbase[b] = bucket_base[b] + blockhist[(size_t)b * NSB + blk];
        lcur[b] = 0;
    }
    __syncthreads();
    long tile0 = (long)blk * TILE3;
    #pragma unroll 4
    for (int i = 0; i < TILE3 / 256; i++) {
        long e = tile0 + t + i * 256;
        if (e < N_EDGES) {
            int d = dst[e];
            int bkt = d >> BSHIFT;
            int p = atomicAdd(&lcur[bkt], 1);
            pairs[lbase[bkt] + p] = (unsigned int)src[e] | ((unsigned int)(d & BMASK) << 24);
        }
    }
}

// ---------- 1e. per-bucket CSR build (128 nodes/bucket) ----------
__global__ __launch_bounds__(256)
void build_csr(const unsigned int* __restrict__ pairs, const int* __restrict__ bucket_base,
               int* __restrict__ row_start, int* __restrict__ csr_src, float* __restrict__ dinv) {
    __shared__ int hist[128];
    __shared__ int cur[128];
    __shared__ int wsum[2];
    int b = blockIdx.x;
    int t = threadIdx.x;
    int beg = bucket_base[b], end = bucket_base[b + 1];
    if (t < 128) hist[t] = 0;
    __syncthreads();
    for (int e = beg + t; e < end; e += 256)
        atomicAdd(&hist[pairs[e] >> 24], 1);
    __syncthreads();
    int v = 0, x = 0;
    int lane = t & 63, wid = t >> 6;
    if (t < 128) {
        v = hist[t];
        x = v;
        #pragma unroll
        for (int off = 1; off < 64; off <<= 1) {
            int y = __shfl_up(x, off, 64);
            if (lane >= off) x += y;
        }
        if (lane == 63) wsum[wid] = x;
    }
    __syncthreads();
    if (t == 0) { int s = wsum[0]; wsum[0] = 0; wsum[1] = s; }
    __syncthreads();
    if (t < 128) {
        int excl = wsum[wid] + (x - v);
        cur[t] = excl;
        int node = b * 128 + t;
        if (node < N_NODES) {
            row_start[node] = beg + excl;
            dinv[node] = rsqrtf(1.0f + (float)v);
        }
    }
    __syncthreads();
    for (int e = beg + t; e < end; e += 256) {
        unsigned int pk = pairs[e];
        int ln = pk >> 24;
        int sp = atomicAdd(&cur[ln], 1);
        csr_src[beg + sp] = (int)(pk & 0xFFFFFFu);
    }
}

// ---------- 2. MFMA GEMM: out = bf16(dinv * (f(in) @ W)) ----------
__global__ __launch_bounds__(256)
void gemm_mfma(const float* __restrict__ inf, const ushort* __restrict__ inb,
               const ushort* __restrict__ wtbT, const float* __restrict__ bnp,
               const float* __restrict__ dinv, ushort* __restrict__ out) {
    __shared__ ushort as_[64][136];
    __shared__ ushort wt[128][136];
    int t = threadIdx.x;
    int wave = t >> 6, lane = t & 63;
    int g = lane >> 4, c = lane & 15;
    int rowbase = blockIdx.x * 64;

    #pragma unroll
    for (int i = 0; i < 8; i++) {
        int cid = t + i * 256;
        int n = cid >> 4, ko = (cid & 15) * 8;
        uint4 v = *(const uint4*)&wtbT[n * 128 + ko];
        *(uint4*)&wt[n][ko] = v;
    }
    if (inf) {
        #pragma unroll
        for (int i = 0; i < 8; i++) {
            int cid = t + i * 256;
            int r = cid >> 5, co = (cid & 31) * 4;
            int row = rowbase + r;
            ushort4 pk = make_ushort4(0, 0, 0, 0);
            if (row < N_NODES) {
                float4 v = *(const float4*)&inf[(size_t)row * HDIM + co];
                pk.x = f2bf(v.x); pk.y = f2bf(v.y); pk.z = f2bf(v.z); pk.w = f2bf(v.w);
            }
            *(ushort4*)&as_[r][co] = pk;
        }
    } else {
        #pragma unroll
        for (int i = 0; i < 4; i++) {
            int cid = t + i * 256;
            int r = cid >> 4, co = (cid & 15) * 8;
            int row = rowbase + r;
            uint4 o = make_uint4(0, 0, 0, 0);
            if (row < N_NODES) {
                uint4 p = *(const uint4*)&inb[(size_t)row * HDIM + co];
                float4 scA = *(const float4*)&bnp[co];
                float4 scB = *(const float4*)&bnp[co + 4];
                float4 shA = *(const float4*)&bnp[128 + co];
                float4 shB = *(const float4*)&bnp[132 + co];
                float v0 = fmaxf(0.f, fmaf(lo16(p.x), scA.x, shA.x));
                float v1 = fmaxf(0.f, fmaf(hi16(p.x), scA.y, shA.y));
                float v2 = fmaxf(0.f, fmaf(lo16(p.y), scA.z, shA.z));
                float v3 = fmaxf(0.f, fmaf(hi16(p.y), scA.w, shA.w));
                float v4 = fmaxf(0.f, fmaf(lo16(p.z), scB.x, shB.x));
                float v5 = fmaxf(0.f, fmaf(hi16(p.z), scB.y, shB.y));
                float v6 = fmaxf(0.f, fmaf(lo16(p.w), scB.z, shB.z));
                float v7 = fmaxf(0.f, fmaf(hi16(p.w), scB.w, shB.w));
                o.x = pack2(v0, v1); o.y = pack2(v2, v3);
                o.z = pack2(v4, v5); o.w = pack2(v6, v7);
            }
            *(uint4*)&as_[r][co] = o;
        }
    }
    __syncthreads();

    int m0 = wave * 16;
    short8_t a[4];
    #pragma unroll
    for (int ch = 0; ch < 4; ch++)
        a[ch] = *(const short8_t*)&as_[m0 + c][ch * 32 + g * 8];
    f32x4_t acc[8] = {};
    #pragma unroll
    for (int ct = 0; ct < 8; ct++) {
        #pragma unroll
        for (int ch = 0; ch < 4; ch++) {
            short8_t b = *(const short8_t*)&wt[ct * 16 + c][ch * 32 + g * 8];
            acc[ct] = __builtin_amdgcn_mfma_f32_16x16x32_bf16(a[ch], b, acc[ct], 0, 0, 0);
        }
    }
    float dv[4];
    #pragma unroll
    for (int reg = 0; reg < 4; reg++) {
        int rr = rowbase + m0 + g * 4 + reg;
        dv[reg] = dinv[rr < N_NODES ? rr : 0];
    }
    __syncthreads();
    #pragma unroll
    for (int ct = 0; ct < 8; ct++)
        #pragma unroll
        for (int reg = 0; reg < 4; reg++)
            as_[m0 + g * 4 + reg][ct * 16 + c] = f2bf(acc[ct][reg] * dv[reg]);
    __syncthreads();
    #pragma unroll
    for (int i = 0; i < 8; i++) {
        int cid = t + i * 256;
        int r = cid >> 5, co = (cid & 31) * 4;
        int row = rowbase + r;
        if (row < N_NODES)
            *(ushort4*)&out[(size_t)row * HDIM + co] = *(const ushort4*)&as_[r][co];
    }
}

// ---------- 3. gather + tail-block BN prep ----------
// agg[n] = bf16(dinv[n]*(sum_e A'[s] + A'[n]) + b). One wave per contiguous node range
// (contiguous -> csr_src index stream is sequential per wave). BN stats: LDS partials ->
// 16 slot-groups via device atomics; last-finishing block reduces and writes bnp.
// NOTE: plain loads on csr_src — NT hint on the index stream measured 2x regression (R7).
__global__ __launch_bounds__(256)
void gather_agg(const ushort* __restrict__ hw, const int* __restrict__ row_start,
                const int* __restrict__ csr_src, const float* __restrict__ dinv,
                const float* __restrict__ bias, ushort* __restrict__ aggout,
                float* __restrict__ slotS, float* __restrict__ slotQ,
                int* __restrict__ counter, const float* __restrict__ gamma,
                const float* __restrict__ beta, float* __restrict__ bnp) {
    __shared__ float s_sum[128];
    __shared__ float s_sq[128];
    __shared__ int isLast;
    int t = threadIdx.x;
    if (t < 128) { s_sum[t] = 0.f; s_sq[t] = 0.f; }
    __syncthreads();
    int lane = t & 63, wid = t >> 6;
    int g = lane >> 4, c = lane & 15;
    int fo = c * 8;
    float4 bA = *(const float4*)&bias[fo];
    float4 bB = *(const float4*)&bias[fo + 4];
    float ls[8] = {}, lq[8] = {};
    int wavesTotal = gridDim.x * 4;
    int chunk = (N_NODES + wavesTotal - 1) / wavesTotal;
    int gw = blockIdx.x * 4 + wid;
    int n0 = gw * chunk;
    int n1 = n0 + chunk; if (n1 > N_NODES) n1 = N_NODES;
    for (int n = n0; n < n1; n++) {
        int jb = row_start[n], je = row_start[n + 1];
        float acc[8] = {};
        int j = jb;
        for (; j + 16 <= je; j += 16) {
            int s0 = csr_src[j + 4 * g + 0];
            int s1 = csr_src[j + 4 * g + 1];
            int s2 = csr_src[j + 4 * g + 2];
            int s3 = csr_src[j + 4 * g + 3];
            uint4 p0 = *(const uint4*)&hw[(size_t)s0 * HDIM + fo];
            uint4 p1 = *(const uint4*)&hw[(size_t)s1 * HDIM + fo];
            uint4 p2 = *(const uint4*)&hw[(size_t)s2 * HDIM + fo];
            uint4 p3 = *(const uint4*)&hw[(size_t)s3 * HDIM + fo];
            acc[0] += (lo16(p0.x) + lo16(p1.x)) + (lo16(p2.x) + lo16(p3.x));
            acc[1] += (hi16(p0.x) + hi16(p1.x)) + (hi16(p2.x) + hi16(p3.x));
            acc[2] += (lo16(p0.y) + lo16(p1.y)) + (lo16(p2.y) + lo16(p3.y));
            acc[3] += (hi16(p0.y) + hi16(p1.y)) + (hi16(p2.y) + hi16(p3.y));
            acc[4] += (lo16(p0.z) + lo16(p1.z)) + (lo16(p2.z) + lo16(p3.z));
            acc[5] += (hi16(p0.z) + hi16(p1.z)) + (hi16(p2.z) + hi16(p3.z));
            acc[6] += (lo16(p0.w) + lo16(p1.w)) + (lo16(p2.w) + lo16(p3.w));
            acc[7] += (hi16(p0.w) + hi16(p1.w)) + (hi16(p2.w) + hi16(p3.w));
        }
        for (; j + 8 <= je; j += 8) {
            int sa = csr_src[j + 2 * g];
            int sb = csr_src[j + 2 * g + 1];
            uint4 p = *(const uint4*)&hw[(size_t)sa * HDIM + fo];
            uint4 q = *(const uint4*)&hw[(size_t)sb * HDIM + fo];
            acc[0] += lo16(p.x) + lo16(q.x);
            acc[1] += hi16(p.x) + hi16(q.x);
            acc[2] += lo16(p.y) + lo16(q.y);
            acc[3] += hi16(p.y) + hi16(q.y);
            acc[4] += lo16(p.z) + lo16(q.z);
            acc[5] += hi16(p.z) + hi16(q.z);
            acc[6] += lo16(p.w) + lo16(q.w);
            acc[7] += hi16(p.w) + hi16(q.w);
        }
        int e0 = j + g, e1 = j + 4 + g;
        if (e0 < je) {
            int s = csr_src[e0];
            uint4 p = *(const uint4*)&hw[(size_t)s * HDIM + fo];
            acc[0] += lo16(p.x); acc[1] += hi16(p.x);
            acc[2] += lo16(p.y); acc[3] += hi16(p.y);
            acc[4] += lo16(p.z); acc[5] += hi16(p.z);
            acc[6] += lo16(p.w); acc[7] += hi16(p.w);
        }
        if (e1 < je) {
            int s = csr_src[e1];
            uint4 p = *(const uint4*)&hw[(size_t)s * HDIM + fo];
            acc[0] += lo16(p.x); acc[1] += hi16(p.x);
            acc[2] += lo16(p.y); acc[3] += hi16(p.y);
            acc[4] += lo16(p.z); acc[5] += hi16(p.z);
            acc[6] += lo16(p.w); acc[7] += hi16(p.w);
        }
        #pragma unroll
        for (int i = 0; i < 8; i++) {
            acc[i] += __shfl_xor(acc[i], 16);
            acc[i] += __shfl_xor(acc[i], 32);
        }
        uint4 ps = *(const uint4*)&hw[(size_t)n * HDIM + fo];
        float dn = dinv[n];
        float r[8];
        r[0] = fmaf(acc[0] + lo16(ps.x), dn, bA.x);
        r[1] = fmaf(acc[1] + hi16(ps.x), dn, bA.y);
        r[2] = fmaf(acc[2] + lo16(ps.y), dn, bA.z);
        r[3] = fmaf(acc[3] + hi16(ps.y), dn, bA.w);
        r[4] = fmaf(acc[4] + lo16(ps.z), dn, bB.x);
        r[5] = fmaf(acc[5] + hi16(ps.z), dn, bB.y);
        r[6] = fmaf(acc[6] + lo16(ps.w), dn, bB.z);
        r[7] = fmaf(acc[7] + hi16(ps.w), dn, bB.w);
        if (g == 0) {
            uint4 o;
            o.x = pack2(r[0], r[1]); o.y = pack2(r[2], r[3]);
            o.z = pack2(r[4], r[5]); o.w = pack2(r[6], r[7]);
            *(uint4*)&aggout[(size_t)n * HDIM + fo] = o;
            #pragma unroll
            for (int i = 0; i < 8; i++) { ls[i] += r[i]; lq[i] += r[i] * r[i]; }
        }
    }
    if (g == 0) {
        #pragma unroll
        for (int i = 0; i < 8; i++) {
            atomicAdd(&s_sum[fo + i], ls[i]);
            atomicAdd(&s_sq[fo + i],  lq[i]);
        }
    }
    __syncthreads();
    int slot = (blockIdx.x & 15) * 128;
    if (t < 128) {
        atomicAdd(&slotS[slot + t], s_sum[t]);
        atomicAdd(&slotQ[slot + t], s_sq[t]);
    }
    __threadfence();
    if (t == 0) isLast = (atomicAdd(counter, 1) == GATHER_BLOCKS - 1);
    __syncthreads();
    if (isLast) {
        __threadfence();
        if (t < 128) {
            float S = 0.f, Q = 0.f;
            #pragma unroll
            for (int s = 0; s < 16; s++) { S += slotS[s * 128 + t]; Q += slotQ[s * 128 + t]; }
            float mean = S * (1.0f / N_NODES);
            float var  = Q * (1.0f / N_NODES) - mean * mean;
            float inv  = rsqrtf(var + BN_EPS);
            float sc   = gamma[t] * inv;
            bnp[t]       = sc;
            bnp[128 + t] = beta[t] - mean * sc;
        }
    }
}

// ---------- 4. fused mean-pool (BN+ReLU) + classifier MLP, one block per graph ----------
__global__ __launch_bounds__(128)
void pool_mlp(const ushort* __restrict__ agg, const float* __restrict__ bnp,
              const int* __restrict__ batch, const float* __restrict__ w1,
              const float* __restrict__ b1, const float* __restrict__ w2,
              const float* __restrict__ b2, float* __restrict__ out) {
    __shared__ float p[128];
    __shared__ float z[64];
    int g = blockIdx.x;
    int k = threadIdx.x;
    int lo = 0, hi = N_NODES;
    while (lo < hi) { int mid = (lo + hi) >> 1; if (batch[mid] < g) lo = mid + 1; else hi = mid; }
    int start = lo;
    hi = N_NODES;
    while (lo < hi) { int mid = (lo + hi) >> 1; if (batch[mid] < g + 1) lo = mid + 1; else hi = mid; }
    int end = lo;
    float sc = bnp[k], sh = bnp[128 + k];
    float sum = 0.f;
    int n = start;
    for (; n + 4 <= end; n += 4) {
        float a0 = bf2f(agg[(size_t)(n + 0) * HDIM + k]);
        float a1 = bf2f(agg[(size_t)(n + 1) * HDIM + k]);
        float a2 = bf2f(agg[(size_t)(n + 2) * HDIM + k]);
        float a3 = bf2f(agg[(size_t)(n + 3) * HDIM + k]);
        sum += fmaxf(0.f, fmaf(a0, sc, sh));
        sum += fmaxf(0.f, fmaf(a1, sc, sh));
        sum += fmaxf(0.f, fmaf(a2, sc, sh));
        sum += fmaxf(0.f, fmaf(a3, sc, sh));
    }
    for (; n < end; n++)
        sum += fmaxf(0.f, fmaf(bf2f(agg[(size_t)n * HDIM + k]), sc, sh));
    float cnt = (float)(end - start);
    p[k] = sum / fmaxf(cnt, 1.0f);
    __syncthreads();
    if (k < 64) {
        float s = b1[k];
        #pragma unroll 8
        for (int kk = 0; kk < 128; kk++) s += p[kk] * w1[kk * 64 + k];
        z[k] = fmaxf(0.f, s);
    }
    __syncthreads();
    if (k < NCLASS) {
        float s = b2[k];
        #pragma unroll
        for (int j = 0; j < 64; j++) s += z[j] * w2[j * NCLASS + k];
        out[g * NCLASS + k] = s;
    }
}

extern "C" void kernel_launch(void* const* d_in, const int* in_sizes, int n_in,
                              void* d_out, int out_size, void* d_ws, size_t ws_size,
                              hipStream_t stream) {
    const float* x      = (const float*)d_in[0];
    const float* conv_w = (const float*)d_in[1];
    const float* conv_b = (const float*)d_in[2];
    const float* gamma  = (const float*)d_in[3];
    const float* beta   = (const float*)d_in[4];
    const float* w1     = (const float*)d_in[5];
    const float* b1     = (const float*)d_in[6];
    const float* w2     = (const float*)d_in[7];
    const float* b2     = (const float*)d_in[8];
    const int*   ei     = (const int*)d_in[9];
    const int*   batch  = (const int*)d_in[10];
    float* out = (float*)d_out;

    char* ws = (char*)d_ws;
    size_t off = 0;
    auto alloc = [&](size_t bytes) -> void* {
        off = (off + 255) & ~(size_t)255;
        void* p = ws + off;
        off += bytes;
        return p;
    };
    ushort* A         = (ushort*)alloc((size_t)N_NODES * HDIM * 2);   // hw (dinv-scaled), bf16
    ushort* aggB      = (ushort*)alloc((size_t)N_NODES * HDIM * 2);   // agg, bf16
    int*    csr_src   = (int*)   alloc((size_t)N_EDGES * 4);
    int*    row_start = (int*)   alloc((size_t)(N_NODES + 1) * 4);
    float*  dinv      = (float*) alloc((size_t)N_NODES * 4);
    int*    blockhist = (int*)   alloc((size_t)NBUCKET * NSB * 4);
    int*    coltotal  = (int*)   alloc((size_t)NBUCKET * 4);
    int*    bbase     = (int*)   alloc((size_t)(NBUCKET + 1) * 4);
    ushort* wtbT      = (ushort*)alloc((size_t)3 * 16384 * 2);
    float*  slotbuf   = (float*) alloc((size_t)3 * 2 * 16 * 128 * 4); // BN stat slots
    int*    counters  = (int*)   alloc(3 * 4);
    float*  bnp       = (float*) alloc(3 * 256 * 4);
    // pairs aliases aggB: aggB is first written by layer-0 gather, after build_csr completes.
    unsigned int* pairs = (unsigned int*)aggB;

    const int* srcv = ei;
    const int* dstv = ei + N_EDGES;

    wprep_hist   <<<48 + NSB, 256, 0, stream>>>(conv_w, wtbT, dstv, blockhist);
    col_scan     <<<NBUCKET, 64, 0, stream>>>(blockhist, coltotal);
    bucket_scan  <<<1, 1024, 0, stream>>>(coltotal, bbase, row_start, slotbuf, counters);
    scatter_pairs<<<NSB, 256, 0, stream>>>(srcv, dstv, bbase, blockhist, pairs);
    build_csr    <<<NBUCKET, 256, 0, stream>>>(pairs, bbase, row_start, csr_src, dinv);

    for (int l = 0; l < 3; l++) {
        gemm_mfma<<<(N_NODES + 63) / 64, 256, 0, stream>>>(
            (l == 0) ? x : nullptr, (l == 0) ? nullptr : aggB,
            wtbT + (size_t)l * 16384,
            (l == 0) ? nullptr : (bnp + (l - 1) * 256), dinv, A);
        gather_agg<<<GATHER_BLOCKS, 256, 0, stream>>>(
            A, row_start, csr_src, dinv, conv_b + l * HDIM, aggB,
            slotbuf + (size_t)l * 4096, slotbuf + (size_t)l * 4096 + 2048,
            counters + l, gamma + l * HDIM, beta + l * HDIM, bnp + l * 256);
    }
    pool_mlp<<<NGRAPH, 128, 0, stream>>>(aggB, bnp + 2 * 256, batch, w1, b1, w2, b2, out);
}

// Round 11
// 492.529 us; speedup vs baseline: 1.4820x; 1.4820x over previous
//
#include <hip/hip_runtime.h>
#include <hip/hip_bf16.h>

#define N_NODES 100000
#define N_EDGES 1600000
#define HDIM    128
#define NGRAPH  1000
#define NCLASS  10
#define BN_EPS  1e-5f

#define BSHIFT  7
#define BMASK   127
#define NBUCKET 782          // ceil(N_NODES / 128)
#define TILE3   4096         // edges per scatter block (391 blocks; 8192/196 was CU-starved)
#define NSB     391          // ceil(N_EDGES / TILE3)
#define GATHER_BLOCKS 1024   // measured: 2048 regresses (L2 contention)

typedef short short8_t __attribute__((ext_vector_type(8)));
typedef float f32x4_t  __attribute__((ext_vector_type(4)));

// ---------- bf16 helpers (manual, RNE) ----------
__device__ __forceinline__ float bf2f(ushort u) {
    union { unsigned int i; float f; } v; v.i = ((unsigned int)u) << 16; return v.f;
}
__device__ __forceinline__ ushort f2bf(float f) {
    union { float f; unsigned int i; } v; v.f = f;
    unsigned int i = v.i;
    unsigned int r = i + 0x7fffu + ((i >> 16) & 1u);
    return (ushort)(r >> 16);
}
__device__ __forceinline__ unsigned int pack2(float a, float b) {
    return (unsigned int)f2bf(a) | ((unsigned int)f2bf(b) << 16);
}
__device__ __forceinline__ float lo16(unsigned int u) {
    union { unsigned int i; float f; } v; v.i = u << 16; return v.f;
}
__device__ __forceinline__ float hi16(unsigned int u) {
    union { unsigned int i; float f; } v; v.i = u & 0xffff0000u; return v.f;
}

// ---------- 1a. fused: W^T bf16 prep (blocks 0..47) + per-block bucket histogram ----------
__global__ __launch_bounds__(256)
void wprep_hist(const float* __restrict__ W, ushort* __restrict__ wtbT,
                const int* __restrict__ dst, int* __restrict__ blockhist) {
    __shared__ int h[NBUCKET];
    int t = threadIdx.x;
    if (blockIdx.x < 48) {
        int l = blockIdx.x >> 4, slice = blockIdx.x & 15;
        int idx = slice * 1024 + t * 4;
        int k = idx >> 7, n = idx & 127;
        float4 w4 = *(const float4*)&W[(size_t)l * 16384 + k * 128 + n];
        ushort* o = wtbT + (size_t)l * 16384;
        o[(n + 0) * 128 + k] = f2bf(w4.x);
        o[(n + 1) * 128 + k] = f2bf(w4.y);
        o[(n + 2) * 128 + k] = f2bf(w4.z);
        o[(n + 3) * 128 + k] = f2bf(w4.w);
        return;
    }
    int blk = blockIdx.x - 48;
    for (int i = t; i < NBUCKET; i += 256) h[i] = 0;
    __syncthreads();
    long tile0 = (long)blk * TILE3;
    #pragma unroll 4
    for (int i = 0; i < TILE3 / 256; i++) {
        long e = tile0 + t + i * 256;
        if (e < N_EDGES) atomicAdd(&h[dst[e] >> BSHIFT], 1);
    }
    __syncthreads();
    for (int b = t; b < NBUCKET; b += 256)
        blockhist[(size_t)b * NSB + blk] = h[b];
}

// ---------- 1b. per-bucket scan across scatter blocks: one wave per bucket ----------
__global__ __launch_bounds__(64)
void col_scan(int* __restrict__ blockhist, int* __restrict__ coltotal) {
    int b = blockIdx.x;
    int lane = threadIdx.x;
    int base = b * NSB;
    int carry = 0;
    for (int r = 0; r < NSB; r += 64) {
        int i = r + lane;
        int v = (i < NSB) ? blockhist[base + i] : 0;
        int x = v;
        #pragma unroll
        for (int off = 1; off < 64; off <<= 1) {
            int y = __shfl_up(x, off, 64);
            if (lane >= off) x += y;
        }
        if (i < NSB) blockhist[base + i] = carry + x - v;
        carry += __shfl(x, 63, 64);
    }
    if (lane == 0) coltotal[b] = carry;
}

// ---------- 1c. bucket scan (one block) ----------
__global__ __launch_bounds__(1024)
void bucket_scan(const int* __restrict__ coltotal, int* __restrict__ bucket_base,
                 int* __restrict__ row_start) {
    __shared__ int wsum[16];
    int t = threadIdx.x, lane = t & 63, wid = t >> 6;
    int v = (t < NBUCKET) ? coltotal[t] : 0;
    int x = v;
    #pragma unroll
    for (int off = 1; off < 64; off <<= 1) {
        int y = __shfl_up(x, off, 64);
        if (lane >= off) x += y;
    }
    if (lane == 63) wsum[wid] = x;
    __syncthreads();
    if (t == 0) {
        int s = 0;
        #pragma unroll
        for (int w = 0; w < 16; w++) { int tmp = wsum[w]; wsum[w] = s; s += tmp; }
    }
    __syncthreads();
    int excl = wsum[wid] + (x - v);
    if (t < NBUCKET) bucket_base[t] = excl;
    if (t == 0) { bucket_base[NBUCKET] = N_EDGES; row_start[N_NODES] = N_EDGES; }
}

// ---------- 1d. scatter: single pass, no re-hist, no global atomics ----------
__global__ __launch_bounds__(256)
void scatter_pairs(const int* __restrict__ src, const int* __restrict__ dst,
                   const int* __restrict__ bucket_base, const int* __restrict__ blockhist,
                   unsigned int* __restrict__ pairs) {
    __shared__ int lbase[NBUCKET];
    __shared__ int lcur[NBUCKET];
    int t = threadIdx.x;
    int blk = blockIdx.x;
    for (int b = t; b < NBUCKET; b += 256) {
        lbase[b] = bucket_base[b] + blockhist[(size_t)b * NSB + blk];
        lcur[b] = 0;
    }
    __syncthreads();
    long tile0 = (long)blk * TILE3;
    #pragma unroll 4
    for (int i = 0; i < TILE3 / 256; i++) {
        long e = tile0 + t + i * 256;
        if (e < N_EDGES) {
            int d = dst[e];
            int bkt = d >> BSHIFT;
            int p = atomicAdd(&lcur[bkt], 1);
            pairs[lbase[bkt] + p] = (unsigned int)src[e] | ((unsigned int)(d & BMASK) << 24);
        }
    }
}

// ---------- 1e. per-bucket CSR build (128 nodes/bucket) ----------
__global__ __launch_bounds__(256)
void build_csr(const unsigned int* __restrict__ pairs, const int* __restrict__ bucket_base,
               int* __restrict__ row_start, int* __restrict__ csr_src, float* __restrict__ dinv) {
    __shared__ int hist[128];
    __shared__ int cur[128];
    __shared__ int wsum[2];
    int b = blockIdx.x;
    int t = threadIdx.x;
    int beg = bucket_base[b], end = bucket_base[b + 1];
    if (t < 128) hist[t] = 0;
    __syncthreads();
    for (int e = beg + t; e < end; e += 256)
        atomicAdd(&hist[pairs[e] >> 24], 1);
    __syncthreads();
    int v = 0, x = 0;
    int lane = t & 63, wid = t >> 6;
    if (t < 128) {
        v = hist[t];
        x = v;
        #pragma unroll
        for (int off = 1; off < 64; off <<= 1) {
            int y = __shfl_up(x, off, 64);
            if (lane >= off) x += y;
        }
        if (lane == 63) wsum[wid] = x;
    }
    __syncthreads();
    if (t == 0) { int s = wsum[0]; wsum[0] = 0; wsum[1] = s; }
    __syncthreads();
    if (t < 128) {
        int excl = wsum[wid] + (x - v);
        cur[t] = excl;
        int node = b * 128 + t;
        if (node < N_NODES) {
            row_start[node] = beg + excl;
            dinv[node] = rsqrtf(1.0f + (float)v);
        }
    }
    __syncthreads();
    for (int e = beg + t; e < end; e += 256) {
        unsigned int pk = pairs[e];
        int ln = pk >> 24;
        int sp = atomicAdd(&cur[ln], 1);
        csr_src[beg + sp] = (int)(pk & 0xFFFFFFu);
    }
}

// ---------- 2. MFMA GEMM: out = bf16(dinv * (f(in) @ W)) ----------
__global__ __launch_bounds__(256)
void gemm_mfma(const float* __restrict__ inf, const ushort* __restrict__ inb,
               const ushort* __restrict__ wtbT, const float* __restrict__ bnp,
               const float* __restrict__ dinv, ushort* __restrict__ out) {
    __shared__ ushort as_[64][136];
    __shared__ ushort wt[128][136];
    int t = threadIdx.x;
    int wave = t >> 6, lane = t & 63;
    int g = lane >> 4, c = lane & 15;
    int rowbase = blockIdx.x * 64;

    #pragma unroll
    for (int i = 0; i < 8; i++) {
        int cid = t + i * 256;
        int n = cid >> 4, ko = (cid & 15) * 8;
        uint4 v = *(const uint4*)&wtbT[n * 128 + ko];
        *(uint4*)&wt[n][ko] = v;
    }
    if (inf) {
        #pragma unroll
        for (int i = 0; i < 8; i++) {
            int cid = t + i * 256;
            int r = cid >> 5, co = (cid & 31) * 4;
            int row = rowbase + r;
            ushort4 pk = make_ushort4(0, 0, 0, 0);
            if (row < N_NODES) {
                float4 v = *(const float4*)&inf[(size_t)row * HDIM + co];
                pk.x = f2bf(v.x); pk.y = f2bf(v.y); pk.z = f2bf(v.z); pk.w = f2bf(v.w);
            }
            *(ushort4*)&as_[r][co] = pk;
        }
    } else {
        #pragma unroll
        for (int i = 0; i < 4; i++) {
            int cid = t + i * 256;
            int r = cid >> 4, co = (cid & 15) * 8;
            int row = rowbase + r;
            uint4 o = make_uint4(0, 0, 0, 0);
            if (row < N_NODES) {
                uint4 p = *(const uint4*)&inb[(size_t)row * HDIM + co];
                float4 scA = *(const float4*)&bnp[co];
                float4 scB = *(const float4*)&bnp[co + 4];
                float4 shA = *(const float4*)&bnp[128 + co];
                float4 shB = *(const float4*)&bnp[132 + co];
                float v0 = fmaxf(0.f, fmaf(lo16(p.x), scA.x, shA.x));
                float v1 = fmaxf(0.f, fmaf(hi16(p.x), scA.y, shA.y));
                float v2 = fmaxf(0.f, fmaf(lo16(p.y), scA.z, shA.z));
                float v3 = fmaxf(0.f, fmaf(hi16(p.y), scA.w, shA.w));
                float v4 = fmaxf(0.f, fmaf(lo16(p.z), scB.x, shB.x));
                float v5 = fmaxf(0.f, fmaf(hi16(p.z), scB.y, shB.y));
                float v6 = fmaxf(0.f, fmaf(lo16(p.w), scB.z, shB.z));
                float v7 = fmaxf(0.f, fmaf(hi16(p.w), scB.w, shB.w));
                o.x = pack2(v0, v1); o.y = pack2(v2, v3);
                o.z = pack2(v4, v5); o.w = pack2(v6, v7);
            }
            *(uint4*)&as_[r][co] = o;
        }
    }
    __syncthreads();

    int m0 = wave * 16;
    short8_t a[4];
    #pragma unroll
    for (int ch = 0; ch < 4; ch++)
        a[ch] = *(const short8_t*)&as_[m0 + c][ch * 32 + g * 8];
    f32x4_t acc[8] = {};
    #pragma unroll
    for (int ct = 0; ct < 8; ct++) {
        #pragma unroll
        for (int ch = 0; ch < 4; ch++) {
            short8_t b = *(const short8_t*)&wt[ct * 16 + c][ch * 32 + g * 8];
            acc[ct] = __builtin_amdgcn_mfma_f32_16x16x32_bf16(a[ch], b, acc[ct], 0, 0, 0);
        }
    }
    float dv[4];
    #pragma unroll
    for (int reg = 0; reg < 4; reg++) {
        int rr = rowbase + m0 + g * 4 + reg;
        dv[reg] = dinv[rr < N_NODES ? rr : 0];
    }
    __syncthreads();
    #pragma unroll
    for (int ct = 0; ct < 8; ct++)
        #pragma unroll
        for (int reg = 0; reg < 4; reg++)
            as_[m0 + g * 4 + reg][ct * 16 + c] = f2bf(acc[ct][reg] * dv[reg]);
    __syncthreads();
    #pragma unroll
    for (int i = 0; i < 8; i++) {
        int cid = t + i * 256;
        int r = cid >> 5, co = (cid & 31) * 4;
        int row = rowbase + r;
        if (row < N_NODES)
            *(ushort4*)&out[(size_t)row * HDIM + co] = *(const ushort4*)&as_[r][co];
    }
}

// ---------- 3. gather: agg[n] = bf16(dinv[n]*(sum_e A'[s] + A'[n]) + b) ----------
// one wave per node (grid-strided; blocked ranges measured neutral-to-worse, R10);
// subgroup g of 16 lanes handles 4 edges/iter; lane loads 16B (8 feats).
// Stats: LDS partials -> private Spart/Qpart stores. DO NOT fuse BN via global slot
// atomics (R7/R10: +90us, end-burst same-address atomic contention). DO NOT NT-hint
// the csr index stream (R7).
__global__ __launch_bounds__(256)
void gather_agg(const ushort* __restrict__ hw, const int* __restrict__ row_start,
                const int* __restrict__ csr_src, const float* __restrict__ dinv,
                const float* __restrict__ bias, ushort* __restrict__ aggout,
                float* __restrict__ Spart, float* __restrict__ Qpart) {
    __shared__ float s_sum[128];
    __shared__ float s_sq[128];
    int t = threadIdx.x;
    if (t < 128) { s_sum[t] = 0.f; s_sq[t] = 0.f; }
    __syncthreads();
    int lane = t & 63, wid = t >> 6;
    int g = lane >> 4, c = lane & 15;
    int fo = c * 8;
    float4 bA = *(const float4*)&bias[fo];
    float4 bB = *(const float4*)&bias[fo + 4];
    float ls[8] = {}, lq[8] = {};
    int gw = blockIdx.x * 4 + wid;
    int nw = gridDim.x * 4;
    for (int n = gw; n < N_NODES; n += nw) {
        int jb = row_start[n], je = row_start[n + 1];
        float acc[8] = {};
        int j = jb;
        for (; j + 16 <= je; j += 16) {
            int s0 = csr_src[j + 4 * g + 0];
            int s1 = csr_src[j + 4 * g + 1];
            int s2 = csr_src[j + 4 * g + 2];
            int s3 = csr_src[j + 4 * g + 3];
            uint4 p0 = *(const uint4*)&hw[(size_t)s0 * HDIM + fo];
            uint4 p1 = *(const uint4*)&hw[(size_t)s1 * HDIM + fo];
            uint4 p2 = *(const uint4*)&hw[(size_t)s2 * HDIM + fo];
            uint4 p3 = *(const uint4*)&hw[(size_t)s3 * HDIM + fo];
            acc[0] += (lo16(p0.x) + lo16(p1.x)) + (lo16(p2.x) + lo16(p3.x));
            acc[1] += (hi16(p0.x) + hi16(p1.x)) + (hi16(p2.x) + hi16(p3.x));
            acc[2] += (lo16(p0.y) + lo16(p1.y)) + (lo16(p2.y) + lo16(p3.y));
            acc[3] += (hi16(p0.y) + hi16(p1.y)) + (hi16(p2.y) + hi16(p3.y));
            acc[4] += (lo16(p0.z) + lo16(p1.z)) + (lo16(p2.z) + lo16(p3.z));
            acc[5] += (hi16(p0.z) + hi16(p1.z)) + (hi16(p2.z) + hi16(p3.z));
            acc[6] += (lo16(p0.w) + lo16(p1.w)) + (lo16(p2.w) + lo16(p3.w));
            acc[7] += (hi16(p0.w) + hi16(p1.w)) + (hi16(p2.w) + hi16(p3.w));
        }
        for (; j + 8 <= je; j += 8) {
            int sa = csr_src[j + 2 * g];
            int sb = csr_src[j + 2 * g + 1];
            uint4 p = *(const uint4*)&hw[(size_t)sa * HDIM + fo];
            uint4 q = *(const uint4*)&hw[(size_t)sb * HDIM + fo];
            acc[0] += lo16(p.x) + lo16(q.x);
            acc[1] += hi16(p.x) + hi16(q.x);
            acc[2] += lo16(p.y) + lo16(q.y);
            acc[3] += hi16(p.y) + hi16(q.y);
            acc[4] += lo16(p.z) + lo16(q.z);
            acc[5] += hi16(p.z) + hi16(q.z);
            acc[6] += lo16(p.w) + lo16(q.w);
            acc[7] += hi16(p.w) + hi16(q.w);
        }
        int e0 = j + g, e1 = j + 4 + g;
        if (e0 < je) {
            int s = csr_src[e0];
            uint4 p = *(const uint4*)&hw[(size_t)s * HDIM + fo];
            acc[0] += lo16(p.x); acc[1] += hi16(p.x);
            acc[2] += lo16(p.y); acc[3] += hi16(p.y);
            acc[4] += lo16(p.z); acc[5] += hi16(p.z);
            acc[6] += lo16(p.w); acc[7] += hi16(p.w);
        }
        if (e1 < je) {
            int s = csr_src[e1];
            uint4 p = *(const uint4*)&hw[(size_t)s * HDIM + fo];
            acc[0] += lo16(p.x); acc[1] += hi16(p.x);
            acc[2] += lo16(p.y); acc[3] += hi16(p.y);
            acc[4] += lo16(p.z); acc[5] += hi16(p.z);
            acc[6] += lo16(p.w); acc[7] += hi16(p.w);
        }
        #pragma unroll
        for (int i = 0; i < 8; i++) {
            acc[i] += __shfl_xor(acc[i], 16);
            acc[i] += __shfl_xor(acc[i], 32);
        }
        uint4 ps = *(const uint4*)&hw[(size_t)n * HDIM + fo];
        float dn = dinv[n];
        float r[8];
        r[0] = fmaf(acc[0] + lo16(ps.x), dn, bA.x);
        r[1] = fmaf(acc[1] + hi16(ps.x), dn, bA.y);
        r[2] = fmaf(acc[2] + lo16(ps.y), dn, bA.z);
        r[3] = fmaf(acc[3] + hi16(ps.y), dn, bA.w);
        r[4] = fmaf(acc[4] + lo16(ps.z), dn, bB.x);
        r[5] = fmaf(acc[5] + hi16(ps.z), dn, bB.y);
        r[6] = fmaf(acc[6] + lo16(ps.w), dn, bB.z);
        r[7] = fmaf(acc[7] + hi16(ps.w), dn, bB.w);
        if (g == 0) {
            uint4 o;
            o.x = pack2(r[0], r[1]); o.y = pack2(r[2], r[3]);
            o.z = pack2(r[4], r[5]); o.w = pack2(r[6], r[7]);
            *(uint4*)&aggout[(size_t)n * HDIM + fo] = o;
            #pragma unroll
            for (int i = 0; i < 8; i++) { ls[i] += r[i]; lq[i] += r[i] * r[i]; }
        }
    }
    if (g == 0) {
        #pragma unroll
        for (int i = 0; i < 8; i++) {
            atomicAdd(&s_sum[fo + i], ls[i]);
            atomicAdd(&s_sq[fo + i],  lq[i]);
        }
    }
    __syncthreads();
    if (t < 128) {
        Spart[(size_t)blockIdx.x * 128 + t] = s_sum[t];
        Qpart[(size_t)blockIdx.x * 128 + t] = s_sq[t];
    }
}

// ---------- 4. BN reduce + prep ----------
__global__ __launch_bounds__(256)
void bn_reduce_prep(const float* __restrict__ Spart, const float* __restrict__ Qpart,
                    const float* __restrict__ gamma, const float* __restrict__ beta,
                    float* __restrict__ bnp) {
    __shared__ float rs[32][8];
    __shared__ float rq[32][8];
    int t = threadIdx.x;
    int fi = t & 7, chunk = t >> 3;
    int f = blockIdx.x * 8 + fi;
    float s = 0.f, q = 0.f;
    for (int b = chunk; b < GATHER_BLOCKS; b += 32) {
        s += Spart[(size_t)b * 128 + f];
        q += Qpart[(size_t)b * 128 + f];
    }
    rs[chunk][fi] = s; rq[chunk][fi] = q;
    __syncthreads();
    if (t < 8) {
        float S = 0.f, Q = 0.f;
        #pragma unroll
        for (int cc = 0; cc < 32; cc++) { S += rs[cc][t]; Q += rq[cc][t]; }
        int ff = blockIdx.x * 8 + t;
        float mean = S * (1.0f / N_NODES);
        float var  = Q * (1.0f / N_NODES) - mean * mean;
        float inv  = rsqrtf(var + BN_EPS);
        float sc   = gamma[ff] * inv;
        bnp[ff]       = sc;
        bnp[128 + ff] = beta[ff] - mean * sc;
    }
}

// ---------- 5. fused mean-pool (BN+ReLU) + classifier MLP, one block per graph ----------
__global__ __launch_bounds__(128)
void pool_mlp(const ushort* __restrict__ agg, const float* __restrict__ bnp,
              const int* __restrict__ batch, const float* __restrict__ w1,
              const float* __restrict__ b1, const float* __restrict__ w2,
              const float* __restrict__ b2, float* __restrict__ out) {
    __shared__ float p[128];
    __shared__ float z[64];
    int g = blockIdx.x;
    int k = threadIdx.x;
    int lo = 0, hi = N_NODES;
    while (lo < hi) { int mid = (lo + hi) >> 1; if (batch[mid] < g) lo = mid + 1; else hi = mid; }
    int start = lo;
    hi = N_NODES;
    while (lo < hi) { int mid = (lo + hi) >> 1; if (batch[mid] < g + 1) lo = mid + 1; else hi = mid; }
    int end = lo;
    float sc = bnp[k], sh = bnp[128 + k];
    float sum = 0.f;
    int n = start;
    for (; n + 4 <= end; n += 4) {
        float a0 = bf2f(agg[(size_t)(n + 0) * HDIM + k]);
        float a1 = bf2f(agg[(size_t)(n + 1) * HDIM + k]);
        float a2 = bf2f(agg[(size_t)(n + 2) * HDIM + k]);
        float a3 = bf2f(agg[(size_t)(n + 3) * HDIM + k]);
        sum += fmaxf(0.f, fmaf(a0, sc, sh));
        sum += fmaxf(0.f, fmaf(a1, sc, sh));
        sum += fmaxf(0.f, fmaf(a2, sc, sh));
        sum += fmaxf(0.f, fmaf(a3, sc, sh));
    }
    for (; n < end; n++)
        sum += fmaxf(0.f, fmaf(bf2f(agg[(size_t)n * HDIM + k]), sc, sh));
    float cnt = (float)(end - start);
    p[k] = sum / fmaxf(cnt, 1.0f);
    __syncthreads();
    if (k < 64) {
        float s = b1[k];
        #pragma unroll 8
        for (int kk = 0; kk < 128; kk++) s += p[kk] * w1[kk * 64 + k];
        z[k] = fmaxf(0.f, s);
    }
    __syncthreads();
    if (k < NCLASS) {
        float s = b2[k];
        #pragma unroll
        for (int j = 0; j < 64; j++) s += z[j] * w2[j * NCLASS + k];
        out[g * NCLASS + k] = s;
    }
}

extern "C" void kernel_launch(void* const* d_in, const int* in_sizes, int n_in,
                              void* d_out, int out_size, void* d_ws, size_t ws_size,
                              hipStream_t stream) {
    const float* x      = (const float*)d_in[0];
    const float* conv_w = (const float*)d_in[1];
    const float* conv_b = (const float*)d_in[2];
    const float* gamma  = (const float*)d_in[3];
    const float* beta   = (const float*)d_in[4];
    const float* w1     = (const float*)d_in[5];
    const float* b1     = (const float*)d_in[6];
    const float* w2     = (const float*)d_in[7];
    const float* b2     = (const float*)d_in[8];
    const int*   ei     = (const int*)d_in[9];
    const int*   batch  = (const int*)d_in[10];
    float* out = (float*)d_out;

    char* ws = (char*)d_ws;
    size_t off = 0;
    auto alloc = [&](size_t bytes) -> void* {
        off = (off + 255) & ~(size_t)255;
        void* p = ws + off;
        off += bytes;
        return p;
    };
    ushort* A         = (ushort*)alloc((size_t)N_NODES * HDIM * 2);   // hw (dinv-scaled), bf16
    ushort* aggB      = (ushort*)alloc((size_t)N_NODES * HDIM * 2);   // agg, bf16
    int*    csr_src   = (int*)   alloc((size_t)N_EDGES * 4);
    int*    row_start = (int*)   alloc((size_t)(N_NODES + 1) * 4);
    float*  dinv      = (float*) alloc((size_t)N_NODES * 4);
    int*    blockhist = (int*)   alloc((size_t)NBUCKET * NSB * 4);
    int*    coltotal  = (int*)   alloc((size_t)NBUCKET * 4);
    int*    bbase     = (int*)   alloc((size_t)(NBUCKET + 1) * 4);
    ushort* wtbT      = (ushort*)alloc((size_t)3 * 16384 * 2);
    float*  Spart     = (float*) alloc((size_t)GATHER_BLOCKS * 128 * 4);
    float*  Qpart     = (float*) alloc((size_t)GATHER_BLOCKS * 128 * 4);
    float*  bnp       = (float*) alloc(3 * 256 * 4);
    // pairs aliases aggB: aggB is first written by layer-0 gather, after build_csr completes.
    unsigned int* pairs = (unsigned int*)aggB;

    const int* srcv = ei;
    const int* dstv = ei + N_EDGES;

    wprep_hist   <<<48 + NSB, 256, 0, stream>>>(conv_w, wtbT, dstv, blockhist);
    col_scan     <<<NBUCKET, 64, 0, stream>>>(blockhist, coltotal);
    bucket_scan  <<<1, 1024, 0, stream>>>(coltotal, bbase, row_start);
    scatter_pairs<<<NSB, 256, 0, stream>>>(srcv, dstv, bbase, blockhist, pairs);
    build_csr    <<<NBUCKET, 256, 0, stream>>>(pairs, bbase, row_start, csr_src, dinv);

    for (int l = 0; l < 3; l++) {
        gemm_mfma<<<(N_NODES + 63) / 64, 256, 0, stream>>>(
            (l == 0) ? x : nullptr, (l == 0) ? nullptr : aggB,
            wtbT + (size_t)l * 16384,
            (l == 0) ? nullptr : (bnp + (l - 1) * 256), dinv, A);
        gather_agg<<<GATHER_BLOCKS, 256, 0, stream>>>(A, row_start, csr_src, dinv,
                                                      conv_b + l * HDIM, aggB, Spart, Qpart);
        bn_reduce_prep<<<16, 256, 0, stream>>>(Spart, Qpart, gamma + l * HDIM,
                                               beta + l * HDIM, bnp + l * 256);
    }
    pool_mlp<<<NGRAPH, 128, 0, stream>>>(aggB, bnp + 2 * 256, batch, w1, b1, w2, b2, out);
}